// Round 3
// baseline (10.530 us; speedup 1.0000x reference)
//
#include <hip/hip_runtime.h>

// CrossCompressUnit, algebraically collapsed:
//   v_out[b,:] = v[b,:]*dot(e[b],w_vv) + e[b,:]*dot(v[b],w_ev) + b_vv
//   e_out[b,:] = v[b,:]*dot(e[b],w_ve) + e[b,:]*dot(v[b],w_ee) + b_ee
// B=8192, D=128. Memory-bound: ~16.8 MB total traffic, floor ~2.7 us.
// R3: 16 lanes per row (4 rows/wave), 32 B/lane row data, 4-step butterfly
// (16 shuffles per wave for 4 rows), 2048 waves total, grid=512.

#define NROWS 8192
#define DIM   128

typedef float floatx4 __attribute__((ext_vector_type(4)));

__device__ __forceinline__ float dot4(floatx4 a, floatx4 b) {
    return a.x*b.x + a.y*b.y + a.z*b.z + a.w*b.w;
}

__global__ __launch_bounds__(256) void ccu_kernel(
    const float* __restrict__ v, const float* __restrict__ e,
    const float* __restrict__ w_vv, const float* __restrict__ b_vv,
    const float* __restrict__ w_ev, const float* __restrict__ w_ve,
    const float* __restrict__ w_ee, const float* __restrict__ b_ee,
    float* __restrict__ out)
{
    const int lane = threadIdx.x & 63;     // wave = 64 on CDNA
    const int wave = threadIdx.x >> 6;     // 4 waves/block
    const int grp  = lane >> 4;            // 4 row-groups of 16 lanes
    const int l16  = lane & 15;

    const int row = (blockIdx.x * 4 + wave) * 4 + grp;  // 16 rows/block
    const int col = l16 * 8;               // each lane owns 8 columns

    const floatx4 vv0 = *reinterpret_cast<const floatx4*>(v + row * DIM + col);
    const floatx4 vv1 = *reinterpret_cast<const floatx4*>(v + row * DIM + col + 4);
    const floatx4 ev0 = *reinterpret_cast<const floatx4*>(e + row * DIM + col);
    const floatx4 ev1 = *reinterpret_cast<const floatx4*>(e + row * DIM + col + 4);

    const floatx4 wvv0 = *reinterpret_cast<const floatx4*>(w_vv + col);
    const floatx4 wvv1 = *reinterpret_cast<const floatx4*>(w_vv + col + 4);
    const floatx4 wev0 = *reinterpret_cast<const floatx4*>(w_ev + col);
    const floatx4 wev1 = *reinterpret_cast<const floatx4*>(w_ev + col + 4);
    const floatx4 wve0 = *reinterpret_cast<const floatx4*>(w_ve + col);
    const floatx4 wve1 = *reinterpret_cast<const floatx4*>(w_ve + col + 4);
    const floatx4 wee0 = *reinterpret_cast<const floatx4*>(w_ee + col);
    const floatx4 wee1 = *reinterpret_cast<const floatx4*>(w_ee + col + 4);

    // per-lane partials of the 4 dot products
    float p0 = dot4(ev0, wvv0) + dot4(ev1, wvv1);  // dot(e, w_vv)
    float p1 = dot4(vv0, wev0) + dot4(vv1, wev1);  // dot(v, w_ev)
    float p2 = dot4(ev0, wve0) + dot4(ev1, wve1);  // dot(e, w_ve)
    float p3 = dot4(vv0, wee0) + dot4(vv1, wee1);  // dot(v, w_ee)

    // 16-lane butterfly (offsets <16 stay within each row-group)
    #pragma unroll
    for (int off = 8; off >= 1; off >>= 1) {
        p0 += __shfl_xor(p0, off, 64);
        p1 += __shfl_xor(p1, off, 64);
        p2 += __shfl_xor(p2, off, 64);
        p3 += __shfl_xor(p3, off, 64);
    }

    const float bvv = b_vv[0];
    const float bee = b_ee[0];

    floatx4 vo0, vo1, eo0, eo1;
    vo0.x = vv0.x*p0 + ev0.x*p1 + bvv;
    vo0.y = vv0.y*p0 + ev0.y*p1 + bvv;
    vo0.z = vv0.z*p0 + ev0.z*p1 + bvv;
    vo0.w = vv0.w*p0 + ev0.w*p1 + bvv;
    vo1.x = vv1.x*p0 + ev1.x*p1 + bvv;
    vo1.y = vv1.y*p0 + ev1.y*p1 + bvv;
    vo1.z = vv1.z*p0 + ev1.z*p1 + bvv;
    vo1.w = vv1.w*p0 + ev1.w*p1 + bvv;
    eo0.x = vv0.x*p2 + ev0.x*p3 + bee;
    eo0.y = vv0.y*p2 + ev0.y*p3 + bee;
    eo0.z = vv0.z*p2 + ev0.z*p3 + bee;
    eo0.w = vv0.w*p2 + ev0.w*p3 + bee;
    eo1.x = vv1.x*p2 + ev1.x*p3 + bee;
    eo1.y = vv1.y*p2 + ev1.y*p3 + bee;
    eo1.z = vv1.z*p2 + ev1.z*p3 + bee;
    eo1.w = vv1.w*p2 + ev1.w*p3 + bee;

    float* vout = out + row * DIM + col;
    float* eout = out + (size_t)NROWS * DIM + row * DIM + col;
    __builtin_nontemporal_store(vo0, reinterpret_cast<floatx4*>(vout));
    __builtin_nontemporal_store(vo1, reinterpret_cast<floatx4*>(vout + 4));
    __builtin_nontemporal_store(eo0, reinterpret_cast<floatx4*>(eout));
    __builtin_nontemporal_store(eo1, reinterpret_cast<floatx4*>(eout + 4));
}

extern "C" void kernel_launch(void* const* d_in, const int* in_sizes, int n_in,
                              void* d_out, int out_size, void* d_ws, size_t ws_size,
                              hipStream_t stream) {
    const float* v    = (const float*)d_in[0];
    const float* e    = (const float*)d_in[1];
    const float* w_vv = (const float*)d_in[2];
    const float* b_vv = (const float*)d_in[3];
    const float* w_ev = (const float*)d_in[4];
    const float* w_ve = (const float*)d_in[5];
    const float* w_ee = (const float*)d_in[6];
    const float* b_ee = (const float*)d_in[7];
    float* out = (float*)d_out;

    // 4 waves/block, 4 rows/wave -> 16 rows/block -> 512 blocks
    const int grid = NROWS / 16;
    ccu_kernel<<<grid, 256, 0, stream>>>(v, e, w_vv, b_vv, w_ev, w_ve, w_ee, b_ee, out);
}